// Round 20
// baseline (169.926 us; speedup 1.0000x reference)
//
#include <hip/hip_runtime.h>
#include <hip/hip_bf16.h>

#define M_N 100000
#define K_F 512
#define N_F 128
#define N_E 1600000
#define NBUK 782           // ceil(100000/128) dst-buckets of 128 nodes
#define CAP 2560           // per-bucket capacity (mean 2046, sd 45 -> +11 sigma)
#define EPB 8192           // edges per bin block -> 196 blocks

typedef __attribute__((ext_vector_type(8))) short bf16x8;
typedef __attribute__((ext_vector_type(4))) float f32x4;

__device__ __forceinline__ unsigned short f2bf(float f) {
  unsigned u = __float_as_uint(f);
  u += 0x7FFFu + ((u >> 16) & 1u);      // RNE
  return (unsigned short)(u >> 16);
}

__device__ __forceinline__ unsigned pkbf(float a, float b) {
  __hip_bfloat162 h = __float22bfloat162_rn(make_float2(a, b));
  return *(unsigned*)&h;                // v_cvt_pk_bf16_f32
}

// ---------- 1) weight f32[512][128] -> bf16^T [128][512]; + init bucket cursors ----------
__global__ void k_wt(const float* __restrict__ w, unsigned short* __restrict__ wtb,
                     int* __restrict__ gcur) {
  int idx = blockIdx.x * 256 + threadIdx.x;     // 65536 total
  if (idx < NBUK) gcur[idx] = idx * CAP;
  int k = idx >> 7, n = idx & 127;
  wtb[n * K_F + k] = f2bf(w[idx]);              // w[idx] == w[k][n]
}

// ---------- 2) GEMM: r12 pipeline + NT|SC1 A staging ----------
// r18 proved the read cap is cache-allocation churn: NT(aux=2) on A gave the
// first gemm win in 8 rounds (112 -> ~98us). A has ~0% L2/L3 hit rate (each
// line read once by one block), so widen the bypass: aux=18 = NT|SC1 ->
// skip L2 allocation too, freeing L2 for B (reused 782x) and S.
__global__ __launch_bounds__(256, 2) void k_gemm(const float* __restrict__ A,
                       const unsigned short* __restrict__ Bt,   // [128][512] bf16
                       unsigned short* __restrict__ S) {        // [M][128] bf16
  __shared__ __align__(16) float As[3][128 * 32];               // 3 x 16KB
  __shared__ __align__(16) unsigned short Bs[3][128 * 32];      // 3 x 8KB
  const int tid = threadIdx.x;
  const int lane = tid & 63;
  const int wv = tid >> 6;
  const int lr = lane & 15, lq = lane >> 4;
  const int bm0 = blockIdx.x * 128;
  const int wrow = wv * 32;

  f32x4 acc[2][8] = {};

#define STAGE(T, BUF)                                                          \
  do {                                                                         \
    _Pragma("unroll") for (int i = 0; i < 4; i++) {                            \
      int idx = i * 256 + tid;                                                 \
      int r = idx >> 3, c = idx & 7;                                           \
      int gr = bm0 + r; if (gr > M_N - 1) gr = M_N - 1;                        \
      const float* srcp = A + (size_t)gr * K_F + (T) * 32 + (c ^ (r & 7)) * 4; \
      __builtin_amdgcn_global_load_lds(                                        \
          (const __attribute__((address_space(1))) void*)srcp,                 \
          (__attribute__((address_space(3))) void*)&As[BUF][(i * 256 + wv * 64) * 4], \
          16, 0, 18 /* NT|SC1: bypass cache allocation entirely */);           \
    }                                                                          \
    _Pragma("unroll") for (int i = 0; i < 2; i++) {                            \
      int idx = i * 256 + tid;                                                 \
      int n = idx >> 2, c = idx & 3;                                           \
      const unsigned short* srcb = Bt + (size_t)n * K_F + (T) * 32 + (c ^ (n & 3)) * 8; \
      __builtin_amdgcn_global_load_lds(                                        \
          (const __attribute__((address_space(1))) void*)srcb,                 \
          (__attribute__((address_space(3))) void*)&Bs[BUF][(i * 256 + wv * 64) * 8], \
          16, 0, 0);                                                           \
    }                                                                          \
  } while (0)

  STAGE(0, 0);
  STAGE(1, 1);

#pragma unroll
  for (int t = 0; t < 16; t++) {
    if (t < 15) asm volatile("s_waitcnt vmcnt(6)" ::: "memory");
    else        asm volatile("s_waitcnt vmcnt(0)" ::: "memory");
    __builtin_amdgcn_sched_barrier(0);
    __builtin_amdgcn_s_barrier();
    __builtin_amdgcn_sched_barrier(0);
    if (t < 14) {
      switch ((t + 2) % 3) {          // compile-time under full unroll
        case 0: STAGE(t + 2, 0); break;
        case 1: STAGE(t + 2, 1); break;
        default: STAGE(t + 2, 2); break;
      }
    }
    const int cb_ = t % 3;
    bf16x8 pb[8];
#pragma unroll
    for (int n = 0; n < 8; n++) {
      int r = n * 16 + lr;
      int cc = lq ^ (r & 3);
      pb[n] = *(const bf16x8*)&Bs[cb_][r * 32 + cc * 8];
    }
#pragma unroll
    for (int m = 0; m < 2; m++) {
      int R = wrow + m * 16 + lr;
      int cb = lq * 2, sw = R & 7;
      f32x4 f0 = *(const f32x4*)&As[cb_][R * 32 + ((cb) ^ sw) * 4];
      f32x4 f1 = *(const f32x4*)&As[cb_][R * 32 + ((cb + 1) ^ sw) * 4];
      uint4 u;
      u.x = pkbf(f0[0], f0[1]);
      u.y = pkbf(f0[2], f0[3]);
      u.z = pkbf(f1[0], f1[1]);
      u.w = pkbf(f1[2], f1[3]);
      bf16x8 af = *(bf16x8*)&u;
#pragma unroll
      for (int n = 0; n < 8; n++)
        acc[m][n] = __builtin_amdgcn_mfma_f32_16x16x32_bf16(af, pb[n], acc[m][n], 0, 0, 0);
    }
  }
#undef STAGE

  // epilogue: D layout col=lane&15, row=(lane>>4)*4+j  [measured m89]
#pragma unroll
  for (int m = 0; m < 2; m++)
#pragma unroll
    for (int j = 0; j < 4; j++) {
      int gr = bm0 + wrow + m * 16 + lq * 4 + j;
      if (gr < M_N) {
#pragma unroll
        for (int n = 0; n < 8; n++)
          S[(size_t)gr * N_F + n * 16 + lr] = f2bf(acc[m][n][j]);
      }
    }
}

// ---------- 3) bin edges by dst>>7; NT loads on the single-use edge streams ----------
__global__ __launch_bounds__(512) void k_bin(const int* __restrict__ src,
                                             const int* __restrict__ dst,
                                             const float* __restrict__ w,
                                             int* __restrict__ gcur,
                                             uint2* __restrict__ ebin) {
  __shared__ int lh[NBUK];
  __shared__ int lb[NBUK];
  const int tid = threadIdx.x;
  const int e0 = blockIdx.x * EPB;
  for (int b = tid; b < NBUK; b += 512) lh[b] = 0;
  __syncthreads();
#pragma unroll
  for (int i = 0; i < EPB / 512; i++) {
    int e = e0 + i * 512 + tid;
    if (e < N_E) atomicAdd(&lh[__builtin_nontemporal_load(&dst[e]) >> 7], 1);
  }
  __syncthreads();
  for (int b = tid; b < NBUK; b += 512) {
    int c = lh[b];
    lb[b] = c ? atomicAdd(&gcur[b], c) : 0;
    lh[b] = 0;                       // reuse as rank cursor
  }
  __syncthreads();
#pragma unroll
  for (int i = 0; i < EPB / 512; i++) {
    int e = e0 + i * 512 + tid;
    if (e < N_E) {
      int d = __builtin_nontemporal_load(&dst[e]);
      int bk = d >> 7;
      int rank = atomicAdd(&lh[bk], 1);
      int s = __builtin_nontemporal_load(&src[e]);
      float wv = __builtin_nontemporal_load(&w[e]);
      ebin[lb[bk] + rank] =
          make_uint2(((unsigned)(d & 127) << 17) | (unsigned)s,
                     __float_as_uint(wv));
    }
  }
}

// ---------- 4) fused bucket sort + SpMM gather + ReLU ----------
__device__ __forceinline__ void fma8(float* acc, float wgt, uint4 v) {
  acc[0] = fmaf(wgt, __uint_as_float(v.x << 16), acc[0]);
  acc[1] = fmaf(wgt, __uint_as_float(v.x & 0xFFFF0000u), acc[1]);
  acc[2] = fmaf(wgt, __uint_as_float(v.y << 16), acc[2]);
  acc[3] = fmaf(wgt, __uint_as_float(v.y & 0xFFFF0000u), acc[3]);
  acc[4] = fmaf(wgt, __uint_as_float(v.z << 16), acc[4]);
  acc[5] = fmaf(wgt, __uint_as_float(v.z & 0xFFFF0000u), acc[5]);
  acc[6] = fmaf(wgt, __uint_as_float(v.w << 16), acc[6]);
  acc[7] = fmaf(wgt, __uint_as_float(v.w & 0xFFFF0000u), acc[7]);
}

__global__ __launch_bounds__(512) void k_bspmm(const unsigned short* __restrict__ S,
                                               const int* __restrict__ gcur,
                                               const uint2* __restrict__ ebin,
                                               float* __restrict__ out) {
  __shared__ uint2 srt[CAP];                 // 20KB sorted edges
  __shared__ int hist[128], excl[129], cur[128];
  const int b = blockIdx.x;
  const int t = threadIdx.x;
  const int cnt = gcur[b] - b * CAP;
  const unsigned long long* eb64 =
      (const unsigned long long*)(ebin + (size_t)b * CAP);

  if (t < 128) hist[t] = 0;
  __syncthreads();

  // edges -> registers (static 5-slot, CAP/512 = 5); NT via u64 (builtin
  // rejects HIP_vector_type pointers)
  uint2 er[5];
  int have = 0;
#pragma unroll
  for (int j = 0; j < 5; j++) {
    int i = j * 512 + t;
    if (i < cnt) {
      unsigned long long q = __builtin_nontemporal_load(&eb64[i]);
      er[j] = make_uint2((unsigned)q, (unsigned)(q >> 32));
      have = j + 1;
    }
  }
#pragma unroll
  for (int j = 0; j < 5; j++)
    if (j < have) atomicAdd(&hist[(er[j].x >> 17) & 127], 1);   // ds_add_u32
  __syncthreads();

  // exclusive scan over 128 counters
  if (t < 128) excl[t + 1] = hist[t];
  if (t == 0) excl[0] = 0;
  __syncthreads();
  for (int off = 1; off < 128; off <<= 1) {
    int v = 0;
    if (t < 128) {
      v = excl[t + 1];
      if (t + 1 > off) v += excl[t + 1 - off];
    }
    __syncthreads();
    if (t < 128) excl[t + 1] = v;
    __syncthreads();
  }
  if (t < 128) cur[t] = excl[t];
  __syncthreads();

  // scatter into sorted LDS array
#pragma unroll
  for (int j = 0; j < 5; j++)
    if (j < have) {
      int dl = (er[j].x >> 17) & 127;
      int r = atomicAdd(&cur[dl], 1);
      srt[r] = er[j];
    }
  __syncthreads();

  // gather: wave wv owns nodes [wv*16, +16)
  const int lane = t & 63, wv = t >> 6;
  const int g = lane >> 4;            // edge subgroup 0..3
  const int l = lane & 15;            // 16B chunk within the 256B row
  for (int nn = 0; nn < 16; nn++) {
    const int ln = wv * 16 + nn;      // local node
    const int s = excl[ln], e = excl[ln + 1];
    float acc[8] = {0.f, 0.f, 0.f, 0.f, 0.f, 0.f, 0.f, 0.f};
    int i = s + g;
    for (; i + 4 < e; i += 8) {       // 2 gathers in flight per group (8/wave)
      uint2 p0 = srt[i];
      uint2 p1 = srt[i + 4];
      uint4 v0 = *(const uint4*)(S + (size_t)(p0.x & 0x1FFFFu) * N_F + l * 8);
      uint4 v1 = *(const uint4*)(S + (size_t)(p1.x & 0x1FFFFu) * N_F + l * 8);
      fma8(acc, __uint_as_float(p0.y), v0);
      fma8(acc, __uint_as_float(p1.y), v1);
    }
    if (i < e) {
      uint2 p = srt[i];
      uint4 v = *(const uint4*)(S + (size_t)(p.x & 0x1FFFFu) * N_F + l * 8);
      fma8(acc, __uint_as_float(p.y), v);
    }
#pragma unroll
    for (int j = 0; j < 8; j++) {
      acc[j] += __shfl_xor(acc[j], 16, 64);
      acc[j] += __shfl_xor(acc[j], 32, 64);
      acc[j] = fmaxf(acc[j], 0.f);
    }
    const int node = b * 128 + ln;
    if (g < 2 && node < M_N) {
      float4 r = make_float4(acc[g * 4 + 0], acc[g * 4 + 1],
                             acc[g * 4 + 2], acc[g * 4 + 3]);
      *(float4*)(out + (size_t)node * N_F + l * 8 + g * 4) = r;
    }
  }
}

extern "C" void kernel_launch(void* const* d_in, const int* in_sizes, int n_in,
                              void* d_out, int out_size, void* d_ws, size_t ws_size,
                              hipStream_t stream) {
  const float* features = (const float*)d_in[0];
  const float* weight   = (const float*)d_in[1];
  const int* edge_src   = (const int*)d_in[2];
  const int* edge_dst   = (const int*)d_in[3];
  const float* edge_w   = (const float*)d_in[4];
  float* out = (float*)d_out;

  // workspace layout (256B-aligned chunks)
  char* ws = (char*)d_ws;
  size_t off = 0;
  unsigned short* support = (unsigned short*)(ws + off); off += (size_t)M_N * N_F * 2;   // 25.6MB
  unsigned short* wtb     = (unsigned short*)(ws + off); off += (size_t)N_F * K_F * 2;   // 128KB
  int* gcur   = (int*)(ws + off); off += 4096;
  uint2* ebin = (uint2*)(ws + off); off += ((size_t)NBUK * CAP + 64) * 8;                // ~16MB

  k_wt<<<256, 256, 0, stream>>>(weight, wtb, gcur);
  k_gemm<<<(M_N + 127) / 128, 256, 0, stream>>>(features, wtb, support);
  k_bin<<<(N_E + EPB - 1) / EPB, 512, 0, stream>>>(edge_src, edge_dst, edge_w, gcur, ebin);
  k_bspmm<<<NBUK, 512, 0, stream>>>(support, gcur, ebin, out);
}

// Round 21
// 166.120 us; speedup vs baseline: 1.0229x; 1.0229x over previous
//
#include <hip/hip_runtime.h>
#include <hip/hip_bf16.h>

#define M_N 100000
#define K_F 512
#define N_F 128
#define N_E 1600000
#define NBUK 782           // ceil(100000/128) dst-buckets of 128 nodes
#define CAP 2560           // per-bucket capacity (mean 2046, sd 45 -> +11 sigma)
#define EPB 8192           // edges per bin block -> 196 blocks

typedef __attribute__((ext_vector_type(8))) short bf16x8;
typedef __attribute__((ext_vector_type(4))) float f32x4;

__device__ __forceinline__ unsigned short f2bf(float f) {
  unsigned u = __float_as_uint(f);
  u += 0x7FFFu + ((u >> 16) & 1u);      // RNE
  return (unsigned short)(u >> 16);
}

__device__ __forceinline__ unsigned pkbf(float a, float b) {
  __hip_bfloat162 h = __float22bfloat162_rn(make_float2(a, b));
  return *(unsigned*)&h;                // v_cvt_pk_bf16_f32
}

// ---------- 1) weight f32[512][128] -> bf16^T [128][512]; + init bucket cursors ----------
__global__ void k_wt(const float* __restrict__ w, unsigned short* __restrict__ wtb,
                     int* __restrict__ gcur) {
  int idx = blockIdx.x * 256 + threadIdx.x;     // 65536 total
  if (idx < NBUK) gcur[idx] = idx * CAP;
  int k = idx >> 7, n = idx & 127;
  wtb[n * K_F + k] = f2bf(w[idx]);              // w[idx] == w[k][n]
}

// ---------- 2) GEMM: r12 pipeline + NT (aux=2) A staging — the proven r18 config ----------
// r18: NT(aux=2) on A staging = 170 -> 155.8us total (cache-allocation churn
// was the read cap). r19's aux=18 (adding SC1, a coherence-scope bit, not an
// allocation hint) REGRESSED to 169.9 -> reverted to aux=2.
__global__ __launch_bounds__(256, 2) void k_gemm(const float* __restrict__ A,
                       const unsigned short* __restrict__ Bt,   // [128][512] bf16
                       unsigned short* __restrict__ S) {        // [M][128] bf16
  __shared__ __align__(16) float As[3][128 * 32];               // 3 x 16KB
  __shared__ __align__(16) unsigned short Bs[3][128 * 32];      // 3 x 8KB
  const int tid = threadIdx.x;
  const int lane = tid & 63;
  const int wv = tid >> 6;
  const int lr = lane & 15, lq = lane >> 4;
  const int bm0 = blockIdx.x * 128;
  const int wrow = wv * 32;

  f32x4 acc[2][8] = {};

#define STAGE(T, BUF)                                                          \
  do {                                                                         \
    _Pragma("unroll") for (int i = 0; i < 4; i++) {                            \
      int idx = i * 256 + tid;                                                 \
      int r = idx >> 3, c = idx & 7;                                           \
      int gr = bm0 + r; if (gr > M_N - 1) gr = M_N - 1;                        \
      const float* srcp = A + (size_t)gr * K_F + (T) * 32 + (c ^ (r & 7)) * 4; \
      __builtin_amdgcn_global_load_lds(                                        \
          (const __attribute__((address_space(1))) void*)srcp,                 \
          (__attribute__((address_space(3))) void*)&As[BUF][(i * 256 + wv * 64) * 4], \
          16, 0, 2 /* NT: bypass cache allocation (r18-proven) */);            \
    }                                                                          \
    _Pragma("unroll") for (int i = 0; i < 2; i++) {                            \
      int idx = i * 256 + tid;                                                 \
      int n = idx >> 2, c = idx & 3;                                           \
      const unsigned short* srcb = Bt + (size_t)n * K_F + (T) * 32 + (c ^ (n & 3)) * 8; \
      __builtin_amdgcn_global_load_lds(                                        \
          (const __attribute__((address_space(1))) void*)srcb,                 \
          (__attribute__((address_space(3))) void*)&Bs[BUF][(i * 256 + wv * 64) * 8], \
          16, 0, 0);                                                           \
    }                                                                          \
  } while (0)

  STAGE(0, 0);
  STAGE(1, 1);

#pragma unroll
  for (int t = 0; t < 16; t++) {
    if (t < 15) asm volatile("s_waitcnt vmcnt(6)" ::: "memory");
    else        asm volatile("s_waitcnt vmcnt(0)" ::: "memory");
    __builtin_amdgcn_sched_barrier(0);
    __builtin_amdgcn_s_barrier();
    __builtin_amdgcn_sched_barrier(0);
    if (t < 14) {
      switch ((t + 2) % 3) {          // compile-time under full unroll
        case 0: STAGE(t + 2, 0); break;
        case 1: STAGE(t + 2, 1); break;
        default: STAGE(t + 2, 2); break;
      }
    }
    const int cb_ = t % 3;
    bf16x8 pb[8];
#pragma unroll
    for (int n = 0; n < 8; n++) {
      int r = n * 16 + lr;
      int cc = lq ^ (r & 3);
      pb[n] = *(const bf16x8*)&Bs[cb_][r * 32 + cc * 8];
    }
#pragma unroll
    for (int m = 0; m < 2; m++) {
      int R = wrow + m * 16 + lr;
      int cb = lq * 2, sw = R & 7;
      f32x4 f0 = *(const f32x4*)&As[cb_][R * 32 + ((cb) ^ sw) * 4];
      f32x4 f1 = *(const f32x4*)&As[cb_][R * 32 + ((cb + 1) ^ sw) * 4];
      uint4 u;
      u.x = pkbf(f0[0], f0[1]);
      u.y = pkbf(f0[2], f0[3]);
      u.z = pkbf(f1[0], f1[1]);
      u.w = pkbf(f1[2], f1[3]);
      bf16x8 af = *(bf16x8*)&u;
#pragma unroll
      for (int n = 0; n < 8; n++)
        acc[m][n] = __builtin_amdgcn_mfma_f32_16x16x32_bf16(af, pb[n], acc[m][n], 0, 0, 0);
    }
  }
#undef STAGE

  // epilogue: D layout col=lane&15, row=(lane>>4)*4+j  [measured m89]
#pragma unroll
  for (int m = 0; m < 2; m++)
#pragma unroll
    for (int j = 0; j < 4; j++) {
      int gr = bm0 + wrow + m * 16 + lq * 4 + j;
      if (gr < M_N) {
#pragma unroll
        for (int n = 0; n < 8; n++)
          S[(size_t)gr * N_F + n * 16 + lr] = f2bf(acc[m][n][j]);
      }
    }
}

// ---------- 3) bin edges by dst>>7; dst CACHED (read twice), src/w NT (read once) ----------
__global__ __launch_bounds__(512) void k_bin(const int* __restrict__ src,
                                             const int* __restrict__ dst,
                                             const float* __restrict__ w,
                                             int* __restrict__ gcur,
                                             uint2* __restrict__ ebin) {
  __shared__ int lh[NBUK];
  __shared__ int lb[NBUK];
  const int tid = threadIdx.x;
  const int e0 = blockIdx.x * EPB;
  for (int b = tid; b < NBUK; b += 512) lh[b] = 0;
  __syncthreads();
#pragma unroll
  for (int i = 0; i < EPB / 512; i++) {
    int e = e0 + i * 512 + tid;
    if (e < N_E) atomicAdd(&lh[dst[e] >> 7], 1);   // cached: re-read in pass 2
  }
  __syncthreads();
  for (int b = tid; b < NBUK; b += 512) {
    int c = lh[b];
    lb[b] = c ? atomicAdd(&gcur[b], c) : 0;
    lh[b] = 0;                       // reuse as rank cursor
  }
  __syncthreads();
#pragma unroll
  for (int i = 0; i < EPB / 512; i++) {
    int e = e0 + i * 512 + tid;
    if (e < N_E) {
      int d = dst[e];
      int bk = d >> 7;
      int rank = atomicAdd(&lh[bk], 1);
      int s = __builtin_nontemporal_load(&src[e]);     // single-use stream
      float wv = __builtin_nontemporal_load(&w[e]);    // single-use stream
      ebin[lb[bk] + rank] =
          make_uint2(((unsigned)(d & 127) << 17) | (unsigned)s,
                     __float_as_uint(wv));
    }
  }
}

// ---------- 4) fused bucket sort + SpMM gather + ReLU ----------
__device__ __forceinline__ void fma8(float* acc, float wgt, uint4 v) {
  acc[0] = fmaf(wgt, __uint_as_float(v.x << 16), acc[0]);
  acc[1] = fmaf(wgt, __uint_as_float(v.x & 0xFFFF0000u), acc[1]);
  acc[2] = fmaf(wgt, __uint_as_float(v.y << 16), acc[2]);
  acc[3] = fmaf(wgt, __uint_as_float(v.y & 0xFFFF0000u), acc[3]);
  acc[4] = fmaf(wgt, __uint_as_float(v.z << 16), acc[4]);
  acc[5] = fmaf(wgt, __uint_as_float(v.z & 0xFFFF0000u), acc[5]);
  acc[6] = fmaf(wgt, __uint_as_float(v.w << 16), acc[6]);
  acc[7] = fmaf(wgt, __uint_as_float(v.w & 0xFFFF0000u), acc[7]);
}

__global__ __launch_bounds__(512) void k_bspmm(const unsigned short* __restrict__ S,
                                               const int* __restrict__ gcur,
                                               const uint2* __restrict__ ebin,
                                               float* __restrict__ out) {
  __shared__ uint2 srt[CAP];                 // 20KB sorted edges
  __shared__ int hist[128], excl[129], cur[128];
  const int b = blockIdx.x;
  const int t = threadIdx.x;
  const int cnt = gcur[b] - b * CAP;
  const unsigned long long* eb64 =
      (const unsigned long long*)(ebin + (size_t)b * CAP);

  if (t < 128) hist[t] = 0;
  __syncthreads();

  // edges -> registers (static 5-slot, CAP/512 = 5); NT via u64 (single-use)
  uint2 er[5];
  int have = 0;
#pragma unroll
  for (int j = 0; j < 5; j++) {
    int i = j * 512 + t;
    if (i < cnt) {
      unsigned long long q = __builtin_nontemporal_load(&eb64[i]);
      er[j] = make_uint2((unsigned)q, (unsigned)(q >> 32));
      have = j + 1;
    }
  }
#pragma unroll
  for (int j = 0; j < 5; j++)
    if (j < have) atomicAdd(&hist[(er[j].x >> 17) & 127], 1);   // ds_add_u32
  __syncthreads();

  // exclusive scan over 128 counters
  if (t < 128) excl[t + 1] = hist[t];
  if (t == 0) excl[0] = 0;
  __syncthreads();
  for (int off = 1; off < 128; off <<= 1) {
    int v = 0;
    if (t < 128) {
      v = excl[t + 1];
      if (t + 1 > off) v += excl[t + 1 - off];
    }
    __syncthreads();
    if (t < 128) excl[t + 1] = v;
    __syncthreads();
  }
  if (t < 128) cur[t] = excl[t];
  __syncthreads();

  // scatter into sorted LDS array
#pragma unroll
  for (int j = 0; j < 5; j++)
    if (j < have) {
      int dl = (er[j].x >> 17) & 127;
      int r = atomicAdd(&cur[dl], 1);
      srt[r] = er[j];
    }
  __syncthreads();

  // gather: wave wv owns nodes [wv*16, +16)
  const int lane = t & 63, wv = t >> 6;
  const int g = lane >> 4;            // edge subgroup 0..3
  const int l = lane & 15;            // 16B chunk within the 256B row
  for (int nn = 0; nn < 16; nn++) {
    const int ln = wv * 16 + nn;      // local node
    const int s = excl[ln], e = excl[ln + 1];
    float acc[8] = {0.f, 0.f, 0.f, 0.f, 0.f, 0.f, 0.f, 0.f};
    int i = s + g;
    for (; i + 4 < e; i += 8) {       // 2 gathers in flight per group (8/wave)
      uint2 p0 = srt[i];
      uint2 p1 = srt[i + 4];
      uint4 v0 = *(const uint4*)(S + (size_t)(p0.x & 0x1FFFFu) * N_F + l * 8);
      uint4 v1 = *(const uint4*)(S + (size_t)(p1.x & 0x1FFFFu) * N_F + l * 8);
      fma8(acc, __uint_as_float(p0.y), v0);
      fma8(acc, __uint_as_float(p1.y), v1);
    }
    if (i < e) {
      uint2 p = srt[i];
      uint4 v = *(const uint4*)(S + (size_t)(p.x & 0x1FFFFu) * N_F + l * 8);
      fma8(acc, __uint_as_float(p.y), v);
    }
#pragma unroll
    for (int j = 0; j < 8; j++) {
      acc[j] += __shfl_xor(acc[j], 16, 64);
      acc[j] += __shfl_xor(acc[j], 32, 64);
      acc[j] = fmaxf(acc[j], 0.f);
    }
    const int node = b * 128 + ln;
    if (g < 2 && node < M_N) {
      float4 r = make_float4(acc[g * 4 + 0], acc[g * 4 + 1],
                             acc[g * 4 + 2], acc[g * 4 + 3]);
      *(float4*)(out + (size_t)node * N_F + l * 8 + g * 4) = r;
    }
  }
}

extern "C" void kernel_launch(void* const* d_in, const int* in_sizes, int n_in,
                              void* d_out, int out_size, void* d_ws, size_t ws_size,
                              hipStream_t stream) {
  const float* features = (const float*)d_in[0];
  const float* weight   = (const float*)d_in[1];
  const int* edge_src   = (const int*)d_in[2];
  const int* edge_dst   = (const int*)d_in[3];
  const float* edge_w   = (const float*)d_in[4];
  float* out = (float*)d_out;

  // workspace layout (256B-aligned chunks)
  char* ws = (char*)d_ws;
  size_t off = 0;
  unsigned short* support = (unsigned short*)(ws + off); off += (size_t)M_N * N_F * 2;   // 25.6MB
  unsigned short* wtb     = (unsigned short*)(ws + off); off += (size_t)N_F * K_F * 2;   // 128KB
  int* gcur   = (int*)(ws + off); off += 4096;
  uint2* ebin = (uint2*)(ws + off); off += ((size_t)NBUK * CAP + 64) * 8;                // ~16MB

  k_wt<<<256, 256, 0, stream>>>(weight, wtb, gcur);
  k_gemm<<<(M_N + 127) / 128, 256, 0, stream>>>(features, wtb, support);
  k_bin<<<(N_E + EPB - 1) / EPB, 512, 0, stream>>>(edge_src, edge_dst, edge_w, gcur, ebin);
  k_bspmm<<<NBUK, 512, 0, stream>>>(support, gcur, ebin, out);
}

// Round 22
// 155.031 us; speedup vs baseline: 1.0961x; 1.0715x over previous
//
#include <hip/hip_runtime.h>
#include <hip/hip_bf16.h>

#define M_N 100000
#define K_F 512
#define N_F 128
#define N_E 1600000
#define NBUK 782           // ceil(100000/128) dst-buckets of 128 nodes
#define CAP 2560           // per-bucket capacity (mean 2046, sd 45 -> +11 sigma)
#define EPB 8192           // edges per bin block -> 196 blocks

typedef __attribute__((ext_vector_type(8))) short bf16x8;
typedef __attribute__((ext_vector_type(4))) float f32x4;

__device__ __forceinline__ unsigned short f2bf(float f) {
  unsigned u = __float_as_uint(f);
  u += 0x7FFFu + ((u >> 16) & 1u);      // RNE
  return (unsigned short)(u >> 16);
}

__device__ __forceinline__ unsigned pkbf(float a, float b) {
  __hip_bfloat162 h = __float22bfloat162_rn(make_float2(a, b));
  return *(unsigned*)&h;                // v_cvt_pk_bf16_f32
}

// ---------- 1) weight f32[512][128] -> bf16^T [128][512]; + init bucket cursors ----------
__global__ void k_wt(const float* __restrict__ w, unsigned short* __restrict__ wtb,
                     int* __restrict__ gcur) {
  int idx = blockIdx.x * 256 + threadIdx.x;     // 65536 total
  if (idx < NBUK) gcur[idx] = idx * CAP;
  int k = idx >> 7, n = idx & 127;
  wtb[n * K_F + k] = f2bf(w[idx]);              // w[idx] == w[k][n]
}

// ---------- 2) GEMM: r12 pipeline + NT (aux=2) A staging — exact r18 config ----------
// r18 (measured best, 155.8us total): NT on A's global_load_lds only. NT on
// scalar loads elsewhere (r19/r21 bisect) REGRESSES ~10us: those streams are
// consumed by many waves crossing the same lines at different times, so the
// no-allocate discard forces HBM re-fetches. NT pays only on bulk staging
// where each line is consumed by exactly one transaction.
__global__ __launch_bounds__(256, 2) void k_gemm(const float* __restrict__ A,
                       const unsigned short* __restrict__ Bt,   // [128][512] bf16
                       unsigned short* __restrict__ S) {        // [M][128] bf16
  __shared__ __align__(16) float As[3][128 * 32];               // 3 x 16KB
  __shared__ __align__(16) unsigned short Bs[3][128 * 32];      // 3 x 8KB
  const int tid = threadIdx.x;
  const int lane = tid & 63;
  const int wv = tid >> 6;
  const int lr = lane & 15, lq = lane >> 4;
  const int bm0 = blockIdx.x * 128;
  const int wrow = wv * 32;

  f32x4 acc[2][8] = {};

#define STAGE(T, BUF)                                                          \
  do {                                                                         \
    _Pragma("unroll") for (int i = 0; i < 4; i++) {                            \
      int idx = i * 256 + tid;                                                 \
      int r = idx >> 3, c = idx & 7;                                           \
      int gr = bm0 + r; if (gr > M_N - 1) gr = M_N - 1;                        \
      const float* srcp = A + (size_t)gr * K_F + (T) * 32 + (c ^ (r & 7)) * 4; \
      __builtin_amdgcn_global_load_lds(                                        \
          (const __attribute__((address_space(1))) void*)srcp,                 \
          (__attribute__((address_space(3))) void*)&As[BUF][(i * 256 + wv * 64) * 4], \
          16, 0, 2 /* NT: bypass cache allocation (r18-proven) */);            \
    }                                                                          \
    _Pragma("unroll") for (int i = 0; i < 2; i++) {                            \
      int idx = i * 256 + tid;                                                 \
      int n = idx >> 2, c = idx & 3;                                           \
      const unsigned short* srcb = Bt + (size_t)n * K_F + (T) * 32 + (c ^ (n & 3)) * 8; \
      __builtin_amdgcn_global_load_lds(                                        \
          (const __attribute__((address_space(1))) void*)srcb,                 \
          (__attribute__((address_space(3))) void*)&Bs[BUF][(i * 256 + wv * 64) * 8], \
          16, 0, 0);                                                           \
    }                                                                          \
  } while (0)

  STAGE(0, 0);
  STAGE(1, 1);

#pragma unroll
  for (int t = 0; t < 16; t++) {
    if (t < 15) asm volatile("s_waitcnt vmcnt(6)" ::: "memory");
    else        asm volatile("s_waitcnt vmcnt(0)" ::: "memory");
    __builtin_amdgcn_sched_barrier(0);
    __builtin_amdgcn_s_barrier();
    __builtin_amdgcn_sched_barrier(0);
    if (t < 14) {
      switch ((t + 2) % 3) {          // compile-time under full unroll
        case 0: STAGE(t + 2, 0); break;
        case 1: STAGE(t + 2, 1); break;
        default: STAGE(t + 2, 2); break;
      }
    }
    const int cb_ = t % 3;
    bf16x8 pb[8];
#pragma unroll
    for (int n = 0; n < 8; n++) {
      int r = n * 16 + lr;
      int cc = lq ^ (r & 3);
      pb[n] = *(const bf16x8*)&Bs[cb_][r * 32 + cc * 8];
    }
#pragma unroll
    for (int m = 0; m < 2; m++) {
      int R = wrow + m * 16 + lr;
      int cb = lq * 2, sw = R & 7;
      f32x4 f0 = *(const f32x4*)&As[cb_][R * 32 + ((cb) ^ sw) * 4];
      f32x4 f1 = *(const f32x4*)&As[cb_][R * 32 + ((cb + 1) ^ sw) * 4];
      uint4 u;
      u.x = pkbf(f0[0], f0[1]);
      u.y = pkbf(f0[2], f0[3]);
      u.z = pkbf(f1[0], f1[1]);
      u.w = pkbf(f1[2], f1[3]);
      bf16x8 af = *(bf16x8*)&u;
#pragma unroll
      for (int n = 0; n < 8; n++)
        acc[m][n] = __builtin_amdgcn_mfma_f32_16x16x32_bf16(af, pb[n], acc[m][n], 0, 0, 0);
    }
  }
#undef STAGE

  // epilogue: D layout col=lane&15, row=(lane>>4)*4+j  [measured m89]
#pragma unroll
  for (int m = 0; m < 2; m++)
#pragma unroll
    for (int j = 0; j < 4; j++) {
      int gr = bm0 + wrow + m * 16 + lq * 4 + j;
      if (gr < M_N) {
#pragma unroll
        for (int n = 0; n < 8; n++)
          S[(size_t)gr * N_F + n * 16 + lr] = f2bf(acc[m][n][j]);
      }
    }
}

// ---------- 3) bin edges by dst>>7 with per-block run reservation (all cached) ----------
__global__ __launch_bounds__(512) void k_bin(const int* __restrict__ src,
                                             const int* __restrict__ dst,
                                             const float* __restrict__ w,
                                             int* __restrict__ gcur,
                                             uint2* __restrict__ ebin) {
  __shared__ int lh[NBUK];
  __shared__ int lb[NBUK];
  const int tid = threadIdx.x;
  const int e0 = blockIdx.x * EPB;
  for (int b = tid; b < NBUK; b += 512) lh[b] = 0;
  __syncthreads();
#pragma unroll
  for (int i = 0; i < EPB / 512; i++) {
    int e = e0 + i * 512 + tid;
    if (e < N_E) atomicAdd(&lh[dst[e] >> 7], 1);
  }
  __syncthreads();
  for (int b = tid; b < NBUK; b += 512) {
    int c = lh[b];
    lb[b] = c ? atomicAdd(&gcur[b], c) : 0;
    lh[b] = 0;                       // reuse as rank cursor
  }
  __syncthreads();
#pragma unroll
  for (int i = 0; i < EPB / 512; i++) {
    int e = e0 + i * 512 + tid;
    if (e < N_E) {
      int d = dst[e];
      int bk = d >> 7;
      int rank = atomicAdd(&lh[bk], 1);
      ebin[lb[bk] + rank] =
          make_uint2(((unsigned)(d & 127) << 17) | (unsigned)src[e],
                     __float_as_uint(w[e]));
    }
  }
}

// ---------- 4) fused bucket sort + SpMM gather + ReLU ----------
__device__ __forceinline__ void fma8(float* acc, float wgt, uint4 v) {
  acc[0] = fmaf(wgt, __uint_as_float(v.x << 16), acc[0]);
  acc[1] = fmaf(wgt, __uint_as_float(v.x & 0xFFFF0000u), acc[1]);
  acc[2] = fmaf(wgt, __uint_as_float(v.y << 16), acc[2]);
  acc[3] = fmaf(wgt, __uint_as_float(v.y & 0xFFFF0000u), acc[3]);
  acc[4] = fmaf(wgt, __uint_as_float(v.z << 16), acc[4]);
  acc[5] = fmaf(wgt, __uint_as_float(v.z & 0xFFFF0000u), acc[5]);
  acc[6] = fmaf(wgt, __uint_as_float(v.w << 16), acc[6]);
  acc[7] = fmaf(wgt, __uint_as_float(v.w & 0xFFFF0000u), acc[7]);
}

__global__ __launch_bounds__(512) void k_bspmm(const unsigned short* __restrict__ S,
                                               const int* __restrict__ gcur,
                                               const uint2* __restrict__ ebin,
                                               float* __restrict__ out) {
  __shared__ uint2 srt[CAP];                 // 20KB sorted edges
  __shared__ int hist[128], excl[129], cur[128];
  const int b = blockIdx.x;
  const int t = threadIdx.x;
  const int cnt = gcur[b] - b * CAP;
  const uint2* eb = ebin + (size_t)b * CAP;

  if (t < 128) hist[t] = 0;
  __syncthreads();

  // edges -> registers (static 5-slot, CAP/512 = 5)
  uint2 er[5];
  int have = 0;
#pragma unroll
  for (int j = 0; j < 5; j++) {
    int i = j * 512 + t;
    if (i < cnt) { er[j] = eb[i]; have = j + 1; }
  }
#pragma unroll
  for (int j = 0; j < 5; j++)
    if (j < have) atomicAdd(&hist[(er[j].x >> 17) & 127], 1);   // ds_add_u32
  __syncthreads();

  // exclusive scan over 128 counters
  if (t < 128) excl[t + 1] = hist[t];
  if (t == 0) excl[0] = 0;
  __syncthreads();
  for (int off = 1; off < 128; off <<= 1) {
    int v = 0;
    if (t < 128) {
      v = excl[t + 1];
      if (t + 1 > off) v += excl[t + 1 - off];
    }
    __syncthreads();
    if (t < 128) excl[t + 1] = v;
    __syncthreads();
  }
  if (t < 128) cur[t] = excl[t];
  __syncthreads();

  // scatter into sorted LDS array
#pragma unroll
  for (int j = 0; j < 5; j++)
    if (j < have) {
      int dl = (er[j].x >> 17) & 127;
      int r = atomicAdd(&cur[dl], 1);
      srt[r] = er[j];
    }
  __syncthreads();

  // gather: wave wv owns nodes [wv*16, +16)
  const int lane = t & 63, wv = t >> 6;
  const int g = lane >> 4;            // edge subgroup 0..3
  const int l = lane & 15;            // 16B chunk within the 256B row
  for (int nn = 0; nn < 16; nn++) {
    const int ln = wv * 16 + nn;      // local node
    const int s = excl[ln], e = excl[ln + 1];
    float acc[8] = {0.f, 0.f, 0.f, 0.f, 0.f, 0.f, 0.f, 0.f};
    int i = s + g;
    for (; i + 4 < e; i += 8) {       // 2 gathers in flight per group (8/wave)
      uint2 p0 = srt[i];
      uint2 p1 = srt[i + 4];
      uint4 v0 = *(const uint4*)(S + (size_t)(p0.x & 0x1FFFFu) * N_F + l * 8);
      uint4 v1 = *(const uint4*)(S + (size_t)(p1.x & 0x1FFFFu) * N_F + l * 8);
      fma8(acc, __uint_as_float(p0.y), v0);
      fma8(acc, __uint_as_float(p1.y), v1);
    }
    if (i < e) {
      uint2 p = srt[i];
      uint4 v = *(const uint4*)(S + (size_t)(p.x & 0x1FFFFu) * N_F + l * 8);
      fma8(acc, __uint_as_float(p.y), v);
    }
#pragma unroll
    for (int j = 0; j < 8; j++) {
      acc[j] += __shfl_xor(acc[j], 16, 64);
      acc[j] += __shfl_xor(acc[j], 32, 64);
      acc[j] = fmaxf(acc[j], 0.f);
    }
    const int node = b * 128 + ln;
    if (g < 2 && node < M_N) {
      float4 r = make_float4(acc[g * 4 + 0], acc[g * 4 + 1],
                             acc[g * 4 + 2], acc[g * 4 + 3]);
      *(float4*)(out + (size_t)node * N_F + l * 8 + g * 4) = r;
    }
  }
}

extern "C" void kernel_launch(void* const* d_in, const int* in_sizes, int n_in,
                              void* d_out, int out_size, void* d_ws, size_t ws_size,
                              hipStream_t stream) {
  const float* features = (const float*)d_in[0];
  const float* weight   = (const float*)d_in[1];
  const int* edge_src   = (const int*)d_in[2];
  const int* edge_dst   = (const int*)d_in[3];
  const float* edge_w   = (const float*)d_in[4];
  float* out = (float*)d_out;

  // workspace layout (256B-aligned chunks)
  char* ws = (char*)d_ws;
  size_t off = 0;
  unsigned short* support = (unsigned short*)(ws + off); off += (size_t)M_N * N_F * 2;   // 25.6MB
  unsigned short* wtb     = (unsigned short*)(ws + off); off += (size_t)N_F * K_F * 2;   // 128KB
  int* gcur   = (int*)(ws + off); off += 4096;
  uint2* ebin = (uint2*)(ws + off); off += ((size_t)NBUK * CAP + 64) * 8;                // ~16MB

  k_wt<<<256, 256, 0, stream>>>(weight, wtb, gcur);
  k_gemm<<<(M_N + 127) / 128, 256, 0, stream>>>(features, wtb, support);
  k_bin<<<(N_E + EPB - 1) / EPB, 512, 0, stream>>>(edge_src, edge_dst, edge_w, gcur, ebin);
  k_bspmm<<<NBUK, 512, 0, stream>>>(support, gcur, ebin, out);
}